// Round 1
// baseline (658.736 us; speedup 1.0000x reference)
//
#include <hip/hip_runtime.h>
#include <hip/hip_bf16.h>
#include <stdint.h>

// LinearTimeSelfAttention on MI355X, round 1: fp32-VALU baseline.
//
// Folding: y = W_out @ (C^T q) + b_out, q = W_q x + b_q
//        => y = Bm @ x + cvec, Bm = A@W_q, A[o,hd] = sum_e W_out[o,he] C[h,d,e],
//           C[h,d,e] = (sum_n e^{k[hd,n]} v[he,n]) / S[hd],  S[hd]=sum_n e^{k}.
// No max-subtraction needed: logits ~N(0,1), exp is fp32-safe.
//
// K1: per 64-col tile: k,v projections (fp32, scalar-cached weights), exp,
//     bf16 round-trip through LDS, accumulate ctx partials + row sums -> ws.
// K2a: reduce partials.  K2b: build A.  K2c: build Bm, cvec.
// K3: y = Bm x + cvec.

#define NPOS 147456      // 384*384
#define NTILES 2304      // NPOS / 64
#define NB1_MAX 1152

__device__ __forceinline__ uint16_t f2bf_bits(float f) {
    uint32_t u = __float_as_uint(f);
    return (uint16_t)((u + 0x7fffu + ((u >> 16) & 1u)) >> 16);   // RNE, no NaN inputs
}
__device__ __forceinline__ float bfu_lo(uint32_t u) { return __uint_as_float(u << 16); }
__device__ __forceinline__ float bfu_hi(uint32_t u) { return __uint_as_float(u & 0xffff0000u); }

// ---------------- K1: k/v projections + exp + partial context ----------------
__global__ __launch_bounds__(256) void k1_ctx(
    const float* __restrict__ x, const float* __restrict__ w_qkv,
    const float* __restrict__ b_qkv, float* __restrict__ cpart, int nb1)
{
    __shared__ uint16_t ev[256][66];   // rows 0..127 = e^k (hd), 128..255 = v (he); +2 pad
    const int t    = threadIdx.x;
    const int lane = t & 63;
    const int wavu = __builtin_amdgcn_readfirstlane(t >> 6);   // force SGPR -> s_loads
    // phase-B mapping: head = wave, 8x8 grid of 4x4 (d,e) tiles
    const int h  = wavu;
    const int td = (t >> 3) & 7, te = t & 7;
    const int d0 = td * 4, e0 = te * 4;

    float cacc[16];
    #pragma unroll
    for (int i = 0; i < 16; ++i) cacc[i] = 0.f;
    float sacc[4] = {0.f, 0.f, 0.f, 0.f};

    for (int tile = blockIdx.x; tile < NTILES; tile += nb1) {
        const int n0 = tile * 64;
        // ---- phase A: each wave computes 64 projection rows for 64 cols ----
        // lane = column; x column (128 ch) loaded to registers, coalesced per c.
        float f[128];
        #pragma unroll
        for (int c = 0; c < 128; ++c) f[c] = x[c * NPOS + n0 + lane];
        const int Rbase = wavu * 64;   // waves 0,1 -> k rows (hd 0..127); 2,3 -> v rows
        for (int r = 0; r < 64; ++r) {
            const int R = Rbase + r;
            const float* __restrict__ wr = w_qkv + (128 + R) * 128;  // k/v weight rows
            float acc = b_qkv[128 + R];
            #pragma unroll
            for (int j = 0; j < 128; ++j) acc = fmaf(wr[j], f[j], acc);
            const float val = (Rbase < 128) ? __expf(acc) : acc;     // wave-uniform branch
            ev[R][lane] = f2bf_bits(val);
        }
        __syncthreads();
        // ---- phase B: ctx[h][d0+i][e0+j] += e_k * v over 64 cols (2 cols/iter) ----
        for (int colp = 0; colp < 32; ++colp) {
            uint32_t eu[4], vu[4];
            #pragma unroll
            for (int i = 0; i < 4; ++i)
                eu[i] = *reinterpret_cast<const uint32_t*>(&ev[h * 32 + d0 + i][2 * colp]);
            #pragma unroll
            for (int i = 0; i < 4; ++i)
                vu[i] = *reinterpret_cast<const uint32_t*>(&ev[128 + h * 32 + e0 + i][2 * colp]);
            if (te == 0) {   // row sums S[hd], reusing the e-values already loaded
                #pragma unroll
                for (int i = 0; i < 4; ++i) sacc[i] += bfu_lo(eu[i]) + bfu_hi(eu[i]);
            }
            #pragma unroll
            for (int i = 0; i < 4; ++i) {
                const float el = bfu_lo(eu[i]), eh = bfu_hi(eu[i]);
                #pragma unroll
                for (int j = 0; j < 4; ++j) {
                    cacc[i * 4 + j] = fmaf(el, bfu_lo(vu[j]), cacc[i * 4 + j]);
                    cacc[i * 4 + j] = fmaf(eh, bfu_hi(vu[j]), cacc[i * 4 + j]);
                }
            }
        }
        __syncthreads();   // protect ev before next tile's phase A
    }
    // write per-block partials: [0..4095] ctx (h*1024 + d*32 + e), [4096..4223] S
    float* __restrict__ dst = cpart + (size_t)blockIdx.x * 4224;
    #pragma unroll
    for (int i = 0; i < 4; ++i)
        #pragma unroll
        for (int j = 0; j < 4; ++j)
            dst[h * 1024 + (d0 + i) * 32 + (e0 + j)] = cacc[i * 4 + j];
    if (te == 0) {
        #pragma unroll
        for (int i = 0; i < 4; ++i) dst[4096 + h * 32 + d0 + i] = sacc[i];
    }
}

// ---------------- K2a: reduce partials (8-way split + atomic combine) ----------------
__global__ void k2a(const float* __restrict__ cpart, float* __restrict__ ctxU, int nb1)
{
    const int u = blockIdx.x * 256 + threadIdx.x;
    if (u >= 4224 * 8) return;
    const int j = u % 4224, p = u / 4224;
    float s = 0.f;
    for (int b = p; b < nb1; b += 8) s += cpart[(size_t)b * 4224 + j];
    atomicAdd(&ctxU[j], s);   // ctxU zeroed by hipMemsetAsync; [4096..4223] = S
}

// ---------------- K2b: A[o,hd] = sum_e W_out[o,he] ctx[h,d,e] / S[hd] ----------------
__global__ void k2b(const float* __restrict__ w_out, const float* __restrict__ ctxU,
                    float* __restrict__ A)
{
    const int tg = blockIdx.x * 256 + threadIdx.x;   // 16384
    const int o = tg >> 7, hd = tg & 127, h = hd >> 5;
    float s = 0.f;
    #pragma unroll
    for (int e = 0; e < 32; ++e)
        s = fmaf(w_out[o * 128 + h * 32 + e], ctxU[hd * 32 + e], s);
    A[tg] = s / ctxU[4096 + hd];
}

// ---------------- K2c: Bm = A @ W_q ; cvec = A b_q + b_out ----------------
__global__ void k2c(const float* __restrict__ A, const float* __restrict__ w_qkv,
                    const float* __restrict__ b_qkv, const float* __restrict__ b_out,
                    float* __restrict__ Bm, float* __restrict__ cvec)
{
    const int tg = blockIdx.x * 256 + threadIdx.x;   // 16384
    const int o = tg >> 7, c = tg & 127;
    float s = 0.f;
    #pragma unroll 8
    for (int hd = 0; hd < 128; ++hd)
        s = fmaf(A[o * 128 + hd], w_qkv[hd * 128 + c], s);   // q rows = w_qkv rows 0..127
    Bm[tg] = s;
    if (tg < 128) {
        float cs = b_out[tg];
        for (int hd = 0; hd < 128; ++hd) cs = fmaf(A[tg * 128 + hd], b_qkv[hd], cs);
        cvec[tg] = cs;
    }
}

// ---------------- K3: y = Bm @ x + cvec ----------------
__global__ __launch_bounds__(256) void k3(
    const float* __restrict__ x, const float* __restrict__ Bm,
    const float* __restrict__ cvec, float* __restrict__ y)
{
    const int lane = threadIdx.x & 63;
    const int wavu = __builtin_amdgcn_readfirstlane(threadIdx.x >> 6);
    const int n0 = blockIdx.x * 64;
    float f[128];
    #pragma unroll
    for (int c = 0; c < 128; ++c) f[c] = x[c * NPOS + n0 + lane];
    for (int r = 0; r < 32; ++r) {
        const int o = wavu * 32 + r;
        const float* __restrict__ br = Bm + o * 128;
        float acc = cvec[o];
        #pragma unroll
        for (int j = 0; j < 128; ++j) acc = fmaf(br[j], f[j], acc);
        y[o * NPOS + n0 + lane] = acc;
    }
}

extern "C" void kernel_launch(void* const* d_in, const int* in_sizes, int n_in,
                              void* d_out, int out_size, void* d_ws, size_t ws_size,
                              hipStream_t stream)
{
    const float* x     = (const float*)d_in[0];
    const float* w_qkv = (const float*)d_in[1];
    const float* b_qkv = (const float*)d_in[2];
    const float* w_out = (const float*)d_in[3];
    const float* b_out = (const float*)d_in[4];
    float* y = (float*)d_out;

    // workspace layout: cpart[nb1][4224] | ctxU[4224] | A[16384] | Bm[16384] | cvec[128]
    const size_t tail = 16896 + 65536 + 65536 + 512;
    int nb1 = NB1_MAX;
    if (ws_size < tail + (size_t)nb1 * 16896) {
        long cap = ((long)ws_size - (long)tail) / 16896;
        nb1 = (int)cap;
        if (nb1 < 1) nb1 = 1;
        if (nb1 > NB1_MAX) nb1 = NB1_MAX;
    }
    char* wsb = (char*)d_ws;
    float* cpart = (float*)wsb;
    float* ctxU  = (float*)(wsb + (size_t)nb1 * 16896);
    float* A     = ctxU + 4224;
    float* Bm    = A + 16384;
    float* cvec  = Bm + 16384;

    hipLaunchKernelGGL(k1_ctx, dim3(nb1), dim3(256), 0, stream, x, w_qkv, b_qkv, cpart, nb1);
    hipMemsetAsync(ctxU, 0, 16896, stream);
    hipLaunchKernelGGL(k2a, dim3(132), dim3(256), 0, stream, cpart, ctxU, nb1);
    hipLaunchKernelGGL(k2b, dim3(64), dim3(256), 0, stream, w_out, ctxU, A);
    hipLaunchKernelGGL(k2c, dim3(64), dim3(256), 0, stream, A, w_qkv, b_qkv, b_out, Bm, cvec);
    hipLaunchKernelGGL(k3, dim3(NTILES), dim3(256), 0, stream, x, Bm, cvec, y);
}

// Round 2
// 217.658 us; speedup vs baseline: 3.0265x; 3.0265x over previous
//
#include <hip/hip_runtime.h>
#include <hip/hip_bf16.h>
#include <stdint.h>

// LinearTimeSelfAttention MI355X, round 2: bf16 MFMA for K1 (k/v proj + context)
// and K3 (y = Bm x + c). Folding identical to round 1:
//   y = Bm @ x + cvec,  Bm = A@W_q,  A[o,hd] = sum_e W_out[o,he] ctx[h,d,e]/S[hd],
//   ctx = sum_n e^k v,  S = sum_n e^k.
//
// K1 per 64-col tile: stage X^T bf16 -> LDS [n][ch]; MFMA P^T[n][kvrow] =
// X^T W^T (+bias); exp on k-rows; pack bf16 -> LDS Pbuf[kvrow][n]; MFMA
// ctx[d][e] += Ek V^T. All fragment reads are single ds_read_b128.

#define NPOS 147456      // 384*384
#define NTILES 2304      // NPOS / 64
#define NB1 768          // 3 blocks/CU * 256 CUs; 3 tiles per block

typedef __attribute__((ext_vector_type(8))) short short8;
typedef __attribute__((ext_vector_type(4))) float floatx4;

__device__ __forceinline__ uint16_t f2bf(float f) {
    uint32_t u = __float_as_uint(f);
    return (uint16_t)((u + 0x7fffu + ((u >> 16) & 1u)) >> 16);   // RNE
}
__device__ __forceinline__ uint32_t pack2(float a, float b) {
    return (uint32_t)f2bf(a) | ((uint32_t)f2bf(b) << 16);
}

// strides in 32-bit LDS words
#define XS_STRIDE 68     // 136 bf16 per n-row (128 ch + 8 pad)
#define PS_STRIDE 36     // 72 bf16 per kvrow (64 n + 8 pad)

// ---------------- K1: projections + exp + partial context (MFMA) ----------------
__global__ __launch_bounds__(256, 3) void k1_ctx(
    const float* __restrict__ x, const float* __restrict__ w_qkv,
    const float* __restrict__ b_qkv, float* __restrict__ cpart, int nb1)
{
    __shared__ uint32_t Xs[64 * XS_STRIDE];    // X^T bf16: [n][ch]
    __shared__ uint32_t Ps[256 * PS_STRIDE];   // P bf16:  [kvrow][n] (rows 0-127 e^k, 128-255 v)

    const int t = threadIdx.x;
    const int lane = t & 63;
    const int wavu = __builtin_amdgcn_readfirstlane(t >> 6);
    const int m = lane & 15, quad = lane >> 4;
    const int kvbase = wavu * 64;              // waves 0,1: k rows; 2,3: v rows
    const bool is_k = (wavu < 2);

    // --- W fragments (B-operand: B[k=ch][n=kvrow]) held in registers ---
    short8 wfr[4][4];                          // [kvtile][kstep]
    float biasv[4];
    #pragma unroll
    for (int kt = 0; kt < 4; ++kt) {
        const int row = 128 + kvbase + kt * 16 + m;
        biasv[kt] = b_qkv[row];
        #pragma unroll
        for (int ks = 0; ks < 4; ++ks) {
            const float* p = w_qkv + row * 128 + ks * 32 + quad * 8;
            short8 w;
            #pragma unroll
            for (int j = 0; j < 8; ++j) w[j] = (short)f2bf(p[j]);
            wfr[kt][ks] = w;
        }
    }

    floatx4 acc2[4];                           // ctx tiles [dt*2+et], head = wavu
    #pragma unroll
    for (int i = 0; i < 4; ++i) acc2[i] = (floatx4){0.f, 0.f, 0.f, 0.f};
    float sacc[4] = {0.f, 0.f, 0.f, 0.f};

    for (int tile = blockIdx.x; tile < NTILES; tile += nb1) {
        const int n0 = tile * 64;
        // ---- stage X^T: lane = n, wave covers ch wavu*32..+31 ----
        {
            const int c0 = wavu * 32;
            #pragma unroll
            for (int i = 0; i < 8; ++i) {
                const int c = c0 + i * 4;
                const float* xp = x + (size_t)c * NPOS + n0 + lane;
                float a0 = xp[0];
                float a1 = xp[NPOS];
                float a2 = xp[2 * NPOS];
                float a3 = xp[3 * NPOS];
                uint2 w; w.x = pack2(a0, a1); w.y = pack2(a2, a3);
                *(uint2*)&Xs[lane * XS_STRIDE + c / 2] = w;
            }
        }
        __syncthreads();   // staging done; also guarantees prev-tile phase-B reads done
        // ---- phase A: P^T[n][kvrow] = X^T W^T + b ----
        #pragma unroll
        for (int nt = 0; nt < 4; ++nt) {
            short8 afr[4];
            #pragma unroll
            for (int ks = 0; ks < 4; ++ks)
                afr[ks] = *(const short8*)&Xs[(nt * 16 + m) * XS_STRIDE + ks * 16 + quad * 4];
            floatx4 pa[4];
            #pragma unroll
            for (int kt = 0; kt < 4; ++kt) pa[kt] = (floatx4){0.f, 0.f, 0.f, 0.f};
            #pragma unroll
            for (int ks = 0; ks < 4; ++ks)
                #pragma unroll
                for (int kt = 0; kt < 4; ++kt)
                    pa[kt] = __builtin_amdgcn_mfma_f32_16x16x32_bf16(afr[ks], wfr[kt][ks], pa[kt], 0, 0, 0);
            // epilogue: bias, exp (k-waves), row-sum partials, pack -> Ps
            #pragma unroll
            for (int kt = 0; kt < 4; ++kt) {
                float v0 = pa[kt][0] + biasv[kt];
                float v1 = pa[kt][1] + biasv[kt];
                float v2 = pa[kt][2] + biasv[kt];
                float v3 = pa[kt][3] + biasv[kt];
                if (is_k) {
                    v0 = __expf(v0); v1 = __expf(v1);
                    v2 = __expf(v2); v3 = __expf(v3);
                    sacc[kt] += (v0 + v1) + (v2 + v3);
                }
                uint2 w; w.x = pack2(v0, v1); w.y = pack2(v2, v3);
                const int kvrow = kvbase + kt * 16 + m;
                *(uint2*)&Ps[kvrow * PS_STRIDE + nt * 8 + quad * 2] = w;
            }
        }
        __syncthreads();   // P complete
        // ---- phase B: ctx[h] += Ek V^T, head h = wavu ----
        #pragma unroll
        for (int ks = 0; ks < 2; ++ks) {
            short8 ea[2], vb[2];
            #pragma unroll
            for (int dt = 0; dt < 2; ++dt)
                ea[dt] = *(const short8*)&Ps[(wavu * 32 + dt * 16 + m) * PS_STRIDE + ks * 16 + quad * 4];
            #pragma unroll
            for (int et = 0; et < 2; ++et)
                vb[et] = *(const short8*)&Ps[(128 + wavu * 32 + et * 16 + m) * PS_STRIDE + ks * 16 + quad * 4];
            #pragma unroll
            for (int dt = 0; dt < 2; ++dt)
                #pragma unroll
                for (int et = 0; et < 2; ++et)
                    acc2[dt * 2 + et] = __builtin_amdgcn_mfma_f32_16x16x32_bf16(ea[dt], vb[et], acc2[dt * 2 + et], 0, 0, 0);
        }
    }
    // ---- write partials: [0..4095] ctx (h*1024 + d*32 + e), [4096..4223] S ----
    float* __restrict__ dst = cpart + (size_t)blockIdx.x * 4224;
    #pragma unroll
    for (int dt = 0; dt < 2; ++dt)
        #pragma unroll
        for (int et = 0; et < 2; ++et)
            #pragma unroll
            for (int r = 0; r < 4; ++r) {
                const int d = dt * 16 + quad * 4 + r, e = et * 16 + m;
                dst[wavu * 1024 + d * 32 + e] = acc2[dt * 2 + et][r];
            }
    if (is_k) {
        #pragma unroll
        for (int kt = 0; kt < 4; ++kt) {
            float s = sacc[kt];
            s += __shfl_down(s, 32, 64);
            s += __shfl_down(s, 16, 64);
            if (lane < 16) dst[4096 + kvbase + kt * 16 + lane] = s;
        }
    }
}

// ---------------- K2a: reduce partials ----------------
__global__ void k2a(const float* __restrict__ cpart, float* __restrict__ ctxU, int nb1)
{
    const int u = blockIdx.x * 256 + threadIdx.x;
    if (u >= 4224 * 8) return;
    const int j = u % 4224, p = u / 4224;
    float s = 0.f;
    for (int b = p; b < nb1; b += 8) s += cpart[(size_t)b * 4224 + j];
    atomicAdd(&ctxU[j], s);
}

// ---------------- K2b: A[o,hd] = sum_e W_out[o,he] ctx[h,d,e] / S[hd] ----------------
__global__ void k2b(const float* __restrict__ w_out, const float* __restrict__ ctxU,
                    float* __restrict__ A)
{
    const int tg = blockIdx.x * 256 + threadIdx.x;   // 16384
    const int o = tg >> 7, hd = tg & 127, h = hd >> 5;
    float s = 0.f;
    #pragma unroll
    for (int e = 0; e < 32; ++e)
        s = fmaf(w_out[o * 128 + h * 32 + e], ctxU[hd * 32 + e], s);
    A[tg] = s / ctxU[4096 + hd];
}

// ---------------- K2c: Bm = A @ W_q ; cvec = A b_q + b_out ----------------
__global__ void k2c(const float* __restrict__ A, const float* __restrict__ w_qkv,
                    const float* __restrict__ b_qkv, const float* __restrict__ b_out,
                    float* __restrict__ Bm, float* __restrict__ cvec)
{
    const int tg = blockIdx.x * 256 + threadIdx.x;   // 16384
    const int o = tg >> 7, c = tg & 127;
    float s = 0.f;
    #pragma unroll 8
    for (int hd = 0; hd < 128; ++hd)
        s = fmaf(A[o * 128 + hd], w_qkv[hd * 128 + c], s);
    Bm[tg] = s;
    if (tg < 128) {
        float cs = b_out[tg];
        for (int hd = 0; hd < 128; ++hd) cs = fmaf(A[tg * 128 + hd], b_qkv[hd], cs);
        cvec[tg] = cs;
    }
}

// ---------------- K3: y = Bm @ x + cvec (MFMA) ----------------
__global__ __launch_bounds__(256) void k3(
    const float* __restrict__ x, const float* __restrict__ Bm,
    const float* __restrict__ cvec, float* __restrict__ y)
{
    __shared__ uint32_t Xs[64 * XS_STRIDE];
    const int t = threadIdx.x, lane = t & 63;
    const int wavu = __builtin_amdgcn_readfirstlane(t >> 6);
    const int m = lane & 15, quad = lane >> 4;
    const int n0 = blockIdx.x * 64;

    // Bm fragments (B-operand: B[k=ch][n=o]) in registers; wave covers 32 o-rows
    short8 bfr[2][4];
    float cv[2];
    #pragma unroll
    for (int ot = 0; ot < 2; ++ot) {
        const int o = (wavu * 2 + ot) * 16 + m;
        cv[ot] = cvec[o];
        #pragma unroll
        for (int ks = 0; ks < 4; ++ks) {
            const float* p = Bm + o * 128 + ks * 32 + quad * 8;
            short8 w;
            #pragma unroll
            for (int j = 0; j < 8; ++j) w[j] = (short)f2bf(p[j]);
            bfr[ot][ks] = w;
        }
    }
    // stage X^T
    {
        const int c0 = wavu * 32;
        #pragma unroll
        for (int i = 0; i < 8; ++i) {
            const int c = c0 + i * 4;
            const float* xp = x + (size_t)c * NPOS + n0 + lane;
            float a0 = xp[0];
            float a1 = xp[NPOS];
            float a2 = xp[2 * NPOS];
            float a3 = xp[3 * NPOS];
            uint2 w; w.x = pack2(a0, a1); w.y = pack2(a2, a3);
            *(uint2*)&Xs[lane * XS_STRIDE + c / 2] = w;
        }
    }
    __syncthreads();
    floatx4 acc[2][4];
    #pragma unroll
    for (int ot = 0; ot < 2; ++ot)
        #pragma unroll
        for (int nt = 0; nt < 4; ++nt) acc[ot][nt] = (floatx4){0.f, 0.f, 0.f, 0.f};
    #pragma unroll
    for (int nt = 0; nt < 4; ++nt) {
        short8 afr[4];
        #pragma unroll
        for (int ks = 0; ks < 4; ++ks)
            afr[ks] = *(const short8*)&Xs[(nt * 16 + m) * XS_STRIDE + ks * 16 + quad * 4];
        #pragma unroll
        for (int ks = 0; ks < 4; ++ks)
            #pragma unroll
            for (int ot = 0; ot < 2; ++ot)
                acc[ot][nt] = __builtin_amdgcn_mfma_f32_16x16x32_bf16(afr[ks], bfr[ot][ks], acc[ot][nt], 0, 0, 0);
    }
    #pragma unroll
    for (int ot = 0; ot < 2; ++ot) {
        const int o = (wavu * 2 + ot) * 16 + m;
        #pragma unroll
        for (int nt = 0; nt < 4; ++nt) {
            floatx4 v = acc[ot][nt];
            v.x += cv[ot]; v.y += cv[ot]; v.z += cv[ot]; v.w += cv[ot];
            *(floatx4*)(y + (size_t)o * NPOS + n0 + nt * 16 + quad * 4) = v;
        }
    }
}

extern "C" void kernel_launch(void* const* d_in, const int* in_sizes, int n_in,
                              void* d_out, int out_size, void* d_ws, size_t ws_size,
                              hipStream_t stream)
{
    const float* x     = (const float*)d_in[0];
    const float* w_qkv = (const float*)d_in[1];
    const float* b_qkv = (const float*)d_in[2];
    const float* w_out = (const float*)d_in[3];
    const float* b_out = (const float*)d_in[4];
    float* y = (float*)d_out;

    // ws: cpart[nb1][4224] | ctxU[4224] | A[16384] | Bm[16384] | cvec[128]
    const size_t tail = (4224 + 16384 + 16384 + 128) * 4;
    int nb1 = NB1;
    if (ws_size < tail + (size_t)nb1 * 16896) {
        long cap = ((long)ws_size - (long)tail) / 16896;
        nb1 = (int)cap;
        if (nb1 < 1) nb1 = 1;
        if (nb1 > NB1) nb1 = NB1;
    }
    char* wsb = (char*)d_ws;
    float* cpart = (float*)wsb;
    float* ctxU  = (float*)(wsb + (size_t)nb1 * 16896);
    float* A     = ctxU + 4224;
    float* Bm    = A + 16384;
    float* cvec  = Bm + 16384;

    hipLaunchKernelGGL(k1_ctx, dim3(nb1), dim3(256), 0, stream, x, w_qkv, b_qkv, cpart, nb1);
    hipMemsetAsync(ctxU, 0, 16896, stream);
    hipLaunchKernelGGL(k2a, dim3(132), dim3(256), 0, stream, cpart, ctxU, nb1);
    hipLaunchKernelGGL(k2b, dim3(64), dim3(256), 0, stream, w_out, ctxU, A);
    hipLaunchKernelGGL(k2c, dim3(64), dim3(256), 0, stream, A, w_qkv, b_qkv, b_out, Bm, cvec);
    hipLaunchKernelGGL(k3, dim3(NTILES), dim3(256), 0, stream, x, Bm, cvec, y);
}

// Round 3
// 206.193 us; speedup vs baseline: 3.1948x; 1.0556x over previous
//
#include <hip/hip_runtime.h>
#include <hip/hip_bf16.h>
#include <stdint.h>

// LinearTimeSelfAttention MI355X, round 3: pipelined K1 (register prefetch +
// double-buffered Xs), HW packed bf16 cvt, merged tail kernels (no memset, no
// atomics). Folding unchanged:
//   y = Bm @ x + cvec,  Bm = A@W_q,  A[o,hd] = sum_e W_out[o,he] ctx[h,d,e]/S[hd],
//   ctx = sum_n e^k v,  S = sum_n e^k.

#define NPOS 147456      // 384*384
#define NTILES 2304      // NPOS / 64
#define NB1 512          // 2 blocks/CU exactly; 4-5 tiles per block

typedef __attribute__((ext_vector_type(8))) short short8;
typedef __attribute__((ext_vector_type(4))) float floatx4;

__device__ __forceinline__ uint16_t f2bf(float f) {
    uint32_t u = __float_as_uint(f);
    return (uint16_t)((u + 0x7fffu + ((u >> 16) & 1u)) >> 16);   // RNE
}
__device__ __forceinline__ uint32_t pack2(float a, float b) {
#if __has_builtin(__builtin_amdgcn_cvt_pk_bf16_f32)
    auto r = __builtin_amdgcn_cvt_pk_bf16_f32(a, b);   // D.lo=bf16(a), D.hi=bf16(b)
    uint32_t u; __builtin_memcpy(&u, &r, sizeof(u));
    return u;
#else
    return (uint32_t)f2bf(a) | ((uint32_t)f2bf(b) << 16);
#endif
}

// strides in 32-bit LDS words
#define XS_STRIDE 68     // 136 bf16 per n-row (128 ch + 8 pad)
#define PS_STRIDE 36     // 72 bf16 per kvrow (64 n + 8 pad)

// ---------------- K1: projections + exp + partial context (MFMA, pipelined) ----------------
__global__ __launch_bounds__(256, 2) void k1_ctx(
    const float* __restrict__ x, const float* __restrict__ w_qkv,
    const float* __restrict__ b_qkv, float* __restrict__ cpart, int nb1)
{
    __shared__ uint32_t Xs[2][64 * XS_STRIDE];   // X^T bf16: [n][ch], double-buffered
    __shared__ uint32_t Ps[256 * PS_STRIDE];     // P bf16: [kvrow][n] (0-127 e^k, 128-255 v)

    const int t = threadIdx.x;
    const int lane = t & 63;
    const int wavu = __builtin_amdgcn_readfirstlane(t >> 6);
    const int m = lane & 15, quad = lane >> 4;
    const int kvbase = wavu * 64;                // waves 0,1: k rows; 2,3: v rows
    const bool is_k = (wavu < 2);
    const int c0 = wavu * 32;                    // wave's 32-channel slab (uniform)

    // --- W fragments (B-operand: B[k=ch][n=kvrow]) in registers ---
    short8 wfr[4][4];
    float biasv[4];
    #pragma unroll
    for (int kt = 0; kt < 4; ++kt) {
        const int row = 128 + kvbase + kt * 16 + m;
        biasv[kt] = b_qkv[row];
        #pragma unroll
        for (int ks = 0; ks < 4; ++ks) {
            const float* p = w_qkv + row * 128 + ks * 32 + quad * 8;
            short8 w;
            #pragma unroll
            for (int j = 0; j < 8; ++j) w[j] = (short)f2bf(p[j]);
            wfr[kt][ks] = w;
        }
    }

    floatx4 acc2[4];
    #pragma unroll
    for (int i = 0; i < 4; ++i) acc2[i] = (floatx4){0.f, 0.f, 0.f, 0.f};
    float sacc[4] = {0.f, 0.f, 0.f, 0.f};

    // ---- prologue: stage first tile into Xs[0] ----
    {
        const int nofs = blockIdx.x * 64 + lane;
        float pf[32];
        #pragma unroll
        for (int i = 0; i < 32; ++i)
            pf[i] = x[(c0 + i) * NPOS + nofs];   // uniform row base + shared voffset
        #pragma unroll
        for (int i = 0; i < 8; ++i) {
            uint2 w;
            w.x = pack2(pf[i * 4 + 0], pf[i * 4 + 1]);
            w.y = pack2(pf[i * 4 + 2], pf[i * 4 + 3]);
            *(uint2*)&Xs[0][lane * XS_STRIDE + (c0 + i * 4) / 2] = w;
        }
    }
    __syncthreads();

    int cur = 0;
    for (int tile = blockIdx.x; tile < NTILES; tile += nb1) {
        const int tn = tile + nb1;
        float pf[32];
        if (tn < NTILES) {                       // block-uniform
            const int nofs = tn * 64 + lane;
            #pragma unroll
            for (int i = 0; i < 32; ++i)
                pf[i] = x[(c0 + i) * NPOS + nofs];
        }
        // ---- phase A: P^T[n][kvrow] = X^T W^T + b ----
        #pragma unroll
        for (int nt = 0; nt < 4; ++nt) {
            short8 afr[4];
            #pragma unroll
            for (int ks = 0; ks < 4; ++ks)
                afr[ks] = *(const short8*)&Xs[cur][(nt * 16 + m) * XS_STRIDE + ks * 16 + quad * 4];
            floatx4 pa[4];
            #pragma unroll
            for (int kt = 0; kt < 4; ++kt) pa[kt] = (floatx4){0.f, 0.f, 0.f, 0.f};
            #pragma unroll
            for (int ks = 0; ks < 4; ++ks)
                #pragma unroll
                for (int kt = 0; kt < 4; ++kt)
                    pa[kt] = __builtin_amdgcn_mfma_f32_16x16x32_bf16(afr[ks], wfr[kt][ks], pa[kt], 0, 0, 0);
            #pragma unroll
            for (int kt = 0; kt < 4; ++kt) {
                float v0 = pa[kt][0] + biasv[kt];
                float v1 = pa[kt][1] + biasv[kt];
                float v2 = pa[kt][2] + biasv[kt];
                float v3 = pa[kt][3] + biasv[kt];
                if (is_k) {
                    v0 = __expf(v0); v1 = __expf(v1);
                    v2 = __expf(v2); v3 = __expf(v3);
                    sacc[kt] += (v0 + v1) + (v2 + v3);
                }
                uint2 w;
                w.x = pack2(v0, v1);
                w.y = pack2(v2, v3);
                const int kvrow = kvbase + kt * 16 + m;
                *(uint2*)&Ps[kvrow * PS_STRIDE + nt * 8 + quad * 2] = w;
            }
        }
        __syncthreads();   // Ps ready
        // ---- phase B: ctx[h=wavu] += Ek V^T ----
        #pragma unroll
        for (int ks = 0; ks < 2; ++ks) {
            short8 ea[2], vb[2];
            #pragma unroll
            for (int dt = 0; dt < 2; ++dt)
                ea[dt] = *(const short8*)&Ps[(wavu * 32 + dt * 16 + m) * PS_STRIDE + ks * 16 + quad * 4];
            #pragma unroll
            for (int et = 0; et < 2; ++et)
                vb[et] = *(const short8*)&Ps[(128 + wavu * 32 + et * 16 + m) * PS_STRIDE + ks * 16 + quad * 4];
            #pragma unroll
            for (int dt = 0; dt < 2; ++dt)
                #pragma unroll
                for (int et = 0; et < 2; ++et)
                    acc2[dt * 2 + et] = __builtin_amdgcn_mfma_f32_16x16x32_bf16(ea[dt], vb[et], acc2[dt * 2 + et], 0, 0, 0);
        }
        // ---- store prefetched tile into the other Xs buffer ----
        if (tn < NTILES) {
            #pragma unroll
            for (int i = 0; i < 8; ++i) {
                uint2 w;
                w.x = pack2(pf[i * 4 + 0], pf[i * 4 + 1]);
                w.y = pack2(pf[i * 4 + 2], pf[i * 4 + 3]);
                *(uint2*)&Xs[cur ^ 1][lane * XS_STRIDE + (c0 + i * 4) / 2] = w;
            }
        }
        __syncthreads();   // Xs[nxt] visible; Ps reads complete
        cur ^= 1;
    }
    // ---- write partials: [0..4095] ctx (h*1024 + d*32 + e), [4096..4223] S ----
    float* __restrict__ dst = cpart + (size_t)blockIdx.x * 4224;
    #pragma unroll
    for (int dt = 0; dt < 2; ++dt)
        #pragma unroll
        for (int et = 0; et < 2; ++et)
            #pragma unroll
            for (int r = 0; r < 4; ++r) {
                const int d = dt * 16 + quad * 4 + r, e = et * 16 + m;
                dst[wavu * 1024 + d * 32 + e] = acc2[dt * 2 + et][r];
            }
    if (is_k) {
        #pragma unroll
        for (int kt = 0; kt < 4; ++kt) {
            float s = sacc[kt];
            s += __shfl_down(s, 32, 64);
            s += __shfl_down(s, 16, 64);
            if (lane < 16) dst[4096 + kvbase + kt * 16 + lane] = s;
        }
    }
}

// ---------------- K2a: reduce nb1 partials -> 8 partials (no atomics) ----------------
__global__ void k2a(const float* __restrict__ cpart, float* __restrict__ ctxP, int nb1)
{
    const int u = blockIdx.x * 256 + threadIdx.x;
    if (u >= 4224 * 8) return;
    const int j = u % 4224, p = u / 4224;
    float s = 0.f;
    for (int b = p; b < nb1; b += 8) s += cpart[(size_t)b * 4224 + j];
    ctxP[p * 4224 + j] = s;
}

// ---------------- K2bc: A-row per block, then Bm row + cvec ----------------
__global__ __launch_bounds__(128) void k2bc(
    const float* __restrict__ ctxP, const float* __restrict__ w_out,
    const float* __restrict__ w_qkv, const float* __restrict__ b_qkv,
    const float* __restrict__ b_out, float* __restrict__ Bm, float* __restrict__ cvec)
{
    __shared__ float ctx33[128 * 33];   // +33 stride: kills 64-way bank conflict
    __shared__ float Ss[128];
    __shared__ float Arow[128];
    __shared__ float red[128];
    const int o = blockIdx.x, t = threadIdx.x;
    for (int j = t; j < 4224; j += 128) {
        float s = 0.f;
        #pragma unroll
        for (int p = 0; p < 8; ++p) s += ctxP[p * 4224 + j];
        if (j < 4096) ctx33[(j >> 5) * 33 + (j & 31)] = s;
        else          Ss[j - 4096] = s;
    }
    __syncthreads();
    {   // A[o][hd], hd = t
        const int h = t >> 5;
        float s = 0.f;
        #pragma unroll
        for (int e = 0; e < 32; ++e)
            s = fmaf(w_out[o * 128 + h * 32 + e], ctx33[t * 33 + e], s);
        Arow[t] = s / Ss[t];
    }
    __syncthreads();
    {   // Bm[o][c], c = t  (q-weights = w_qkv rows 0..127)
        float s = 0.f;
        #pragma unroll 16
        for (int hd = 0; hd < 128; ++hd)
            s = fmaf(Arow[hd], w_qkv[hd * 128 + t], s);
        Bm[o * 128 + t] = s;
    }
    red[t] = Arow[t] * b_qkv[t];
    __syncthreads();
    if (t == 0) {
        float cs = b_out[o];
        #pragma unroll 8
        for (int i = 0; i < 128; ++i) cs += red[i];
        cvec[o] = cs;
    }
}

// ---------------- K3: y = Bm @ x + cvec (MFMA) ----------------
__global__ __launch_bounds__(256) void k3(
    const float* __restrict__ x, const float* __restrict__ Bm,
    const float* __restrict__ cvec, float* __restrict__ y)
{
    __shared__ uint32_t Xs[64 * XS_STRIDE];
    const int t = threadIdx.x, lane = t & 63;
    const int wavu = __builtin_amdgcn_readfirstlane(t >> 6);
    const int m = lane & 15, quad = lane >> 4;
    const int n0 = blockIdx.x * 64;
    const int c0 = wavu * 32;

    short8 bfr[2][4];
    float cv[2];
    #pragma unroll
    for (int ot = 0; ot < 2; ++ot) {
        const int o = (wavu * 2 + ot) * 16 + m;
        cv[ot] = cvec[o];
        #pragma unroll
        for (int ks = 0; ks < 4; ++ks) {
            const float* p = Bm + o * 128 + ks * 32 + quad * 8;
            short8 w;
            #pragma unroll
            for (int j = 0; j < 8; ++j) w[j] = (short)f2bf(p[j]);
            bfr[ot][ks] = w;
        }
    }
    {
        const int nofs = n0 + lane;
        float pf[32];
        #pragma unroll
        for (int i = 0; i < 32; ++i)
            pf[i] = x[(c0 + i) * NPOS + nofs];
        #pragma unroll
        for (int i = 0; i < 8; ++i) {
            uint2 w;
            w.x = pack2(pf[i * 4 + 0], pf[i * 4 + 1]);
            w.y = pack2(pf[i * 4 + 2], pf[i * 4 + 3]);
            *(uint2*)&Xs[lane * XS_STRIDE + (c0 + i * 4) / 2] = w;
        }
    }
    __syncthreads();
    floatx4 acc[2][4];
    #pragma unroll
    for (int ot = 0; ot < 2; ++ot)
        #pragma unroll
        for (int nt = 0; nt < 4; ++nt) acc[ot][nt] = (floatx4){0.f, 0.f, 0.f, 0.f};
    #pragma unroll
    for (int nt = 0; nt < 4; ++nt) {
        short8 afr[4];
        #pragma unroll
        for (int ks = 0; ks < 4; ++ks)
            afr[ks] = *(const short8*)&Xs[(nt * 16 + m) * XS_STRIDE + ks * 16 + quad * 4];
        #pragma unroll
        for (int ks = 0; ks < 4; ++ks)
            #pragma unroll
            for (int ot = 0; ot < 2; ++ot)
                acc[ot][nt] = __builtin_amdgcn_mfma_f32_16x16x32_bf16(afr[ks], bfr[ot][ks], acc[ot][nt], 0, 0, 0);
    }
    #pragma unroll
    for (int ot = 0; ot < 2; ++ot) {
        const int o = (wavu * 2 + ot) * 16 + m;
        #pragma unroll
        for (int nt = 0; nt < 4; ++nt) {
            floatx4 v = acc[ot][nt];
            v.x += cv[ot]; v.y += cv[ot]; v.z += cv[ot]; v.w += cv[ot];
            *(floatx4*)(y + (size_t)o * NPOS + n0 + nt * 16 + quad * 4) = v;
        }
    }
}

extern "C" void kernel_launch(void* const* d_in, const int* in_sizes, int n_in,
                              void* d_out, int out_size, void* d_ws, size_t ws_size,
                              hipStream_t stream)
{
    const float* x     = (const float*)d_in[0];
    const float* w_qkv = (const float*)d_in[1];
    const float* b_qkv = (const float*)d_in[2];
    const float* w_out = (const float*)d_in[3];
    const float* b_out = (const float*)d_in[4];
    float* y = (float*)d_out;

    // ws: cpart[nb1][4224] | ctxP[8][4224] | Bm[16384] | cvec[128]
    const size_t tail = (size_t)(8 * 4224 + 16384 + 128) * 4;
    int nb1 = NB1;
    if (ws_size < tail + (size_t)nb1 * 16896) {
        long cap = ((long)ws_size - (long)tail) / 16896;
        nb1 = (int)cap;
        if (nb1 < 1) nb1 = 1;
        if (nb1 > NB1) nb1 = NB1;
    }
    char* wsb = (char*)d_ws;
    float* cpart = (float*)wsb;
    float* ctxP  = (float*)(wsb + (size_t)nb1 * 16896);
    float* Bm    = ctxP + 8 * 4224;
    float* cvec  = Bm + 16384;

    hipLaunchKernelGGL(k1_ctx, dim3(nb1), dim3(256), 0, stream, x, w_qkv, b_qkv, cpart, nb1);
    hipLaunchKernelGGL(k2a, dim3(132), dim3(256), 0, stream, cpart, ctxP, nb1);
    hipLaunchKernelGGL(k2bc, dim3(128), dim3(128), 0, stream, ctxP, w_out, w_qkv, b_qkv, b_out, Bm, cvec);
    hipLaunchKernelGGL(k3, dim3(NTILES), dim3(256), 0, stream, x, Bm, cvec, y);
}

// Round 4
// 203.811 us; speedup vs baseline: 3.2321x; 1.0117x over previous
//
#include <hip/hip_runtime.h>
#include <hip/hip_bf16.h>
#include <stdint.h>

// LinearTimeSelfAttention MI355X, round 4:
//  - k1: per-head wave mapping (wave h computes k/v rows of head h only) ->
//    phase B reads only wave-private LDS -> ONE barrier per tile (Xs swap).
//  - k1: register prefetch depth 2 (covers ~900cyc HBM latency).
//  - k2bc: emits bf16-packed Bm rows; k3 fragment build = 8 dwordx4 loads.
// Folding unchanged: y = Bm@x + cvec; Bm = A@W_q; A = (W_out ctx)/S;
// ctx = sum_n e^k v^T; S = sum_n e^k.

#define NPOS 147456      // 384*384
#define NTILES 2304      // NPOS / 64
#define NB1 512          // 2 blocks/CU exactly

typedef __attribute__((ext_vector_type(8))) short short8;
typedef __attribute__((ext_vector_type(4))) float floatx4;

__device__ __forceinline__ uint16_t f2bf(float f) {
    uint32_t u = __float_as_uint(f);
    return (uint16_t)((u + 0x7fffu + ((u >> 16) & 1u)) >> 16);   // RNE
}
__device__ __forceinline__ uint32_t pack2(float a, float b) {
#if __has_builtin(__builtin_amdgcn_cvt_pk_bf16_f32)
    auto r = __builtin_amdgcn_cvt_pk_bf16_f32(a, b);
    uint32_t u; __builtin_memcpy(&u, &r, sizeof(u));
    return u;
#else
    return (uint32_t)f2bf(a) | ((uint32_t)f2bf(b) << 16);
#endif
}

// strides in 32-bit LDS words
#define XS_STRIDE 68     // 136 bf16 per n-row (128 ch + 8 pad)
#define PS_STRIDE 36     // 72 bf16 per kvrow (64 n + 8 pad)

// ---- k1 helpers ----
__device__ __forceinline__ void k1_load(const float* __restrict__ xb, float* pf) {
    #pragma unroll
    for (int i = 0; i < 32; ++i) pf[i] = xb[(size_t)i * NPOS];
}
__device__ __forceinline__ void k1_store(uint32_t* Xsbuf, const float* pf, int lane, int c0) {
    #pragma unroll
    for (int i = 0; i < 8; ++i) {
        uint2 w;
        w.x = pack2(pf[i * 4 + 0], pf[i * 4 + 1]);
        w.y = pack2(pf[i * 4 + 2], pf[i * 4 + 3]);
        *(uint2*)&Xsbuf[lane * XS_STRIDE + (c0 + i * 4) / 2] = w;
    }
}
__device__ __forceinline__ void k1_tile(
    const uint32_t* __restrict__ Xsbuf, uint32_t* __restrict__ Psw,
    const short8 (&wfr)[4][4], const float (&biasv)[4],
    floatx4 (&acc2)[4], float (&sacc)[2], int m, int quad)
{
    // phase A: P^T[n][local kvrow] = X^T W^T + b   (local rows: 0-31 k, 32-63 v)
    #pragma unroll
    for (int nt = 0; nt < 4; ++nt) {
        short8 afr[4];
        #pragma unroll
        for (int ks = 0; ks < 4; ++ks)
            afr[ks] = *(const short8*)&Xsbuf[(nt * 16 + m) * XS_STRIDE + ks * 16 + quad * 4];
        floatx4 pa[4];
        #pragma unroll
        for (int kt = 0; kt < 4; ++kt) pa[kt] = (floatx4){0.f, 0.f, 0.f, 0.f};
        #pragma unroll
        for (int ks = 0; ks < 4; ++ks)
            #pragma unroll
            for (int kt = 0; kt < 4; ++kt)
                pa[kt] = __builtin_amdgcn_mfma_f32_16x16x32_bf16(afr[ks], wfr[kt][ks], pa[kt], 0, 0, 0);
        #pragma unroll
        for (int kt = 0; kt < 4; ++kt) {
            float v0 = pa[kt][0] + biasv[kt];
            float v1 = pa[kt][1] + biasv[kt];
            float v2 = pa[kt][2] + biasv[kt];
            float v3 = pa[kt][3] + biasv[kt];
            if (kt < 2) {   // k rows of this head
                v0 = __expf(v0); v1 = __expf(v1);
                v2 = __expf(v2); v3 = __expf(v3);
                sacc[kt] += (v0 + v1) + (v2 + v3);
            }
            uint2 w;
            w.x = pack2(v0, v1);
            w.y = pack2(v2, v3);
            *(uint2*)&Psw[(kt * 16 + m) * PS_STRIDE + nt * 8 + quad * 2] = w;
        }
    }
    // phase B: ctx += Ek V^T — reads ONLY this wave's Ps region (no barrier)
    #pragma unroll
    for (int ks = 0; ks < 2; ++ks) {
        short8 ea[2], vb[2];
        #pragma unroll
        for (int dt = 0; dt < 2; ++dt)
            ea[dt] = *(const short8*)&Psw[(dt * 16 + m) * PS_STRIDE + ks * 16 + quad * 4];
        #pragma unroll
        for (int et = 0; et < 2; ++et)
            vb[et] = *(const short8*)&Psw[(32 + et * 16 + m) * PS_STRIDE + ks * 16 + quad * 4];
        #pragma unroll
        for (int dt = 0; dt < 2; ++dt)
            #pragma unroll
            for (int et = 0; et < 2; ++et)
                acc2[dt * 2 + et] = __builtin_amdgcn_mfma_f32_16x16x32_bf16(ea[dt], vb[et], acc2[dt * 2 + et], 0, 0, 0);
    }
}

// ---------------- K1: projections + exp + partial context ----------------
__global__ __launch_bounds__(256, 2) void k1_ctx(
    const float* __restrict__ x, const float* __restrict__ w_qkv,
    const float* __restrict__ b_qkv, float* __restrict__ cpart, int nb1)
{
    __shared__ uint32_t Xs[2][64 * XS_STRIDE];
    __shared__ uint32_t Ps[256 * PS_STRIDE];     // 4 wave-private 64-row regions

    const int t = threadIdx.x;
    const int lane = t & 63;
    const int wavu = __builtin_amdgcn_readfirstlane(t >> 6);
    const int m = lane & 15, quad = lane >> 4;
    const int c0 = wavu * 32;
    uint32_t* const Psw = &Ps[wavu * 64 * PS_STRIDE];

    // W fragments: wave h holds k-rows h*32..+31 (kt 0,1) and v-rows h*32..+31 (kt 2,3)
    short8 wfr[4][4];
    float biasv[4];
    #pragma unroll
    for (int kt = 0; kt < 4; ++kt) {
        const int row = (kt < 2 ? 128 + wavu * 32 + kt * 16
                                : 256 + wavu * 32 + (kt - 2) * 16) + m;
        biasv[kt] = b_qkv[row];
        #pragma unroll
        for (int ks = 0; ks < 4; ++ks) {
            const float* p = w_qkv + row * 128 + ks * 32 + quad * 8;
            short8 w;
            #pragma unroll
            for (int j = 0; j < 8; ++j) w[j] = (short)f2bf(p[j]);
            wfr[kt][ks] = w;
        }
    }

    floatx4 acc2[4];
    #pragma unroll
    for (int i = 0; i < 4; ++i) acc2[i] = (floatx4){0.f, 0.f, 0.f, 0.f};
    float sacc[2] = {0.f, 0.f};

    const float* xw = x + (size_t)c0 * NPOS + lane;   // wave's channel slab base
    float pfA[32], pfB[32];

    // prologue: load tiles b, b+nb1; stage b into Xs[0]
    k1_load(xw + blockIdx.x * 64, pfA);
    if (blockIdx.x + nb1 < NTILES) k1_load(xw + (blockIdx.x + nb1) * 64, pfB);
    k1_store(Xs[0], pfA, lane, c0);
    __syncthreads();

    for (int tile = blockIdx.x; tile < NTILES; tile += 2 * nb1) {
        const int t1 = tile + nb1, t2 = tile + 2 * nb1, t3 = tile + 3 * nb1;
        // --- half 1: consume Xs[0] (tile), prefetch t2 -> pfA, stage pfB(t1) -> Xs[1]
        if (t2 < NTILES) k1_load(xw + t2 * 64, pfA);
        k1_tile(Xs[0], Psw, wfr, biasv, acc2, sacc, m, quad);
        if (t1 < NTILES) k1_store(Xs[1], pfB, lane, c0);
        __syncthreads();
        // --- half 2: consume Xs[1] (t1), prefetch t3 -> pfB, stage pfA(t2) -> Xs[0]
        if (t1 < NTILES) {
            if (t3 < NTILES) k1_load(xw + t3 * 64, pfB);
            k1_tile(Xs[1], Psw, wfr, biasv, acc2, sacc, m, quad);
            if (t2 < NTILES) k1_store(Xs[0], pfA, lane, c0);
            __syncthreads();
        }
    }

    // partials: [0..4095] ctx (h*1024 + d*32 + e), [4096..4223] S
    float* __restrict__ dst = cpart + (size_t)blockIdx.x * 4224;
    #pragma unroll
    for (int dt = 0; dt < 2; ++dt)
        #pragma unroll
        for (int et = 0; et < 2; ++et)
            #pragma unroll
            for (int r = 0; r < 4; ++r) {
                const int d = dt * 16 + quad * 4 + r, e = et * 16 + m;
                dst[wavu * 1024 + d * 32 + e] = acc2[dt * 2 + et][r];
            }
    #pragma unroll
    for (int kt = 0; kt < 2; ++kt) {
        float s = sacc[kt];
        s += __shfl_down(s, 32, 64);
        s += __shfl_down(s, 16, 64);
        if (lane < 16) dst[4096 + wavu * 32 + kt * 16 + lane] = s;
    }
}

// ---------------- K2a: reduce nb1 partials -> 8 partials ----------------
__global__ void k2a(const float* __restrict__ cpart, float* __restrict__ ctxP, int nb1)
{
    const int u = blockIdx.x * 256 + threadIdx.x;
    if (u >= 4224 * 8) return;
    const int j = u % 4224, p = u / 4224;
    float s = 0.f;
    for (int b = p; b < nb1; b += 8) s += cpart[(size_t)b * 4224 + j];
    ctxP[p * 4224 + j] = s;
}

// ---------------- K2bc: per-o A row -> bf16 Bm row + cvec ----------------
__global__ __launch_bounds__(128) void k2bc(
    const float* __restrict__ ctxP, const float* __restrict__ w_out,
    const float* __restrict__ w_qkv, const float* __restrict__ b_qkv,
    const float* __restrict__ b_out, uint32_t* __restrict__ Bmb, float* __restrict__ cvec)
{
    __shared__ float ctx33[128 * 33];
    __shared__ float Ss[128];
    __shared__ float Arow[128];
    __shared__ float row[128];
    __shared__ float red[128];
    const int o = blockIdx.x, t = threadIdx.x;
    for (int j = t; j < 4224; j += 128) {
        float s = 0.f;
        #pragma unroll
        for (int p = 0; p < 8; ++p) s += ctxP[p * 4224 + j];
        if (j < 4096) ctx33[(j >> 5) * 33 + (j & 31)] = s;
        else          Ss[j - 4096] = s;
    }
    __syncthreads();
    {   // A[o][hd], hd = t
        const int h = t >> 5;
        float s = 0.f;
        #pragma unroll
        for (int e = 0; e < 32; ++e)
            s = fmaf(w_out[o * 128 + h * 32 + e], ctx33[t * 33 + e], s);
        Arow[t] = s / Ss[t];
    }
    __syncthreads();
    {   // Bm[o][c], c = t
        float s = 0.f;
        #pragma unroll 16
        for (int hd = 0; hd < 128; ++hd)
            s = fmaf(Arow[hd], w_qkv[hd * 128 + t], s);
        row[t] = s;
    }
    red[t] = Arow[t] * b_qkv[t];
    __syncthreads();
    if (t < 64) Bmb[o * 64 + t] = pack2(row[2 * t], row[2 * t + 1]);
    if (t == 0) {
        float cs = b_out[o];
        #pragma unroll 8
        for (int i = 0; i < 128; ++i) cs += red[i];
        cvec[o] = cs;
    }
}

// ---------------- K3: y = Bm @ x + cvec ----------------
__global__ __launch_bounds__(256) void k3(
    const float* __restrict__ x, const uint32_t* __restrict__ Bmb,
    const float* __restrict__ cvec, float* __restrict__ y)
{
    __shared__ uint32_t Xs[64 * XS_STRIDE];
    const int t = threadIdx.x, lane = t & 63;
    const int wavu = __builtin_amdgcn_readfirstlane(t >> 6);
    const int m = lane & 15, quad = lane >> 4;
    const int n0 = blockIdx.x * 64;
    const int c0 = wavu * 32;

    // stage X^T first (get loads in flight)
    float pf[32];
    k1_load(x + (size_t)c0 * NPOS + n0 + lane, pf);

    // Bm fragments from packed bf16 rows: 8 x dwordx4
    short8 bfr[2][4];
    float cv[2];
    #pragma unroll
    for (int ot = 0; ot < 2; ++ot) {
        const int o = (wavu * 2 + ot) * 16 + m;
        cv[ot] = cvec[o];
        #pragma unroll
        for (int ks = 0; ks < 4; ++ks)
            bfr[ot][ks] = *(const short8*)&Bmb[o * 64 + ks * 16 + quad * 4];
    }
    k1_store(Xs, pf, lane, c0);
    __syncthreads();

    floatx4 acc[2][4];
    #pragma unroll
    for (int ot = 0; ot < 2; ++ot)
        #pragma unroll
        for (int nt = 0; nt < 4; ++nt) acc[ot][nt] = (floatx4){0.f, 0.f, 0.f, 0.f};
    #pragma unroll
    for (int nt = 0; nt < 4; ++nt) {
        short8 afr[4];
        #pragma unroll
        for (int ks = 0; ks < 4; ++ks)
            afr[ks] = *(const short8*)&Xs[(nt * 16 + m) * XS_STRIDE + ks * 16 + quad * 4];
        #pragma unroll
        for (int ks = 0; ks < 4; ++ks)
            #pragma unroll
            for (int ot = 0; ot < 2; ++ot)
                acc[ot][nt] = __builtin_amdgcn_mfma_f32_16x16x32_bf16(afr[ks], bfr[ot][ks], acc[ot][nt], 0, 0, 0);
    }
    #pragma unroll
    for (int ot = 0; ot < 2; ++ot) {
        const int o = (wavu * 2 + ot) * 16 + m;
        #pragma unroll
        for (int nt = 0; nt < 4; ++nt) {
            floatx4 v = acc[ot][nt];
            v.x += cv[ot]; v.y += cv[ot]; v.z += cv[ot]; v.w += cv[ot];
            *(floatx4*)(y + (size_t)o * NPOS + n0 + nt * 16 + quad * 4) = v;
        }
    }
}

extern "C" void kernel_launch(void* const* d_in, const int* in_sizes, int n_in,
                              void* d_out, int out_size, void* d_ws, size_t ws_size,
                              hipStream_t stream)
{
    const float* x     = (const float*)d_in[0];
    const float* w_qkv = (const float*)d_in[1];
    const float* b_qkv = (const float*)d_in[2];
    const float* w_out = (const float*)d_in[3];
    const float* b_out = (const float*)d_in[4];
    float* y = (float*)d_out;

    // ws: cpart[nb1][4224] | ctxP[8][4224] | Bmb[8192 u32] | cvec[128]
    const size_t tail = (size_t)(8 * 4224 + 8192 + 128) * 4;
    int nb1 = NB1;
    if (ws_size < tail + (size_t)nb1 * 16896) {
        long cap = ((long)ws_size - (long)tail) / 16896;
        nb1 = (int)cap;
        if (nb1 < 1) nb1 = 1;
        if (nb1 > NB1) nb1 = NB1;
    }
    char* wsb = (char*)d_ws;
    float* cpart   = (float*)wsb;
    float* ctxP    = (float*)(wsb + (size_t)nb1 * 16896);
    uint32_t* Bmb  = (uint32_t*)(ctxP + 8 * 4224);
    float* cvec    = (float*)(Bmb + 8192);

    hipLaunchKernelGGL(k1_ctx, dim3(nb1), dim3(256), 0, stream, x, w_qkv, b_qkv, cpart, nb1);
    hipLaunchKernelGGL(k2a, dim3(132), dim3(256), 0, stream, cpart, ctxP, nb1);
    hipLaunchKernelGGL(k2bc, dim3(128), dim3(128), 0, stream, ctxP, w_out, w_qkv, b_qkv, b_out, Bmb, cvec);
    hipLaunchKernelGGL(k3, dim3(NTILES), dim3(256), 0, stream, x, Bmb, cvec, y);
}